// Round 5
// baseline (43372.144 us; speedup 1.0000x reference)
//
#include <hip/hip_runtime.h>

typedef __attribute__((ext_vector_type(8))) short short8v;
typedef __attribute__((ext_vector_type(4))) float f32x4;
typedef unsigned short u16;

#define MFMA_BF16(a,b,c) __builtin_amdgcn_mfma_f32_16x16x32_bf16((a),(b),(c),0,0,0)

static constexpr int Bb = 256, Tt = 512;

static constexpr size_t MU_OFF  = (size_t)Bb * Tt * 2;            // out: [B,T,2]
static constexpr size_t LV_OFF  = MU_OFF  + (size_t)Bb * Tt * 256;
static constexpr size_t MUP_OFF = LV_OFF  + (size_t)Bb * Tt * 256;
static constexpr size_t LVP_OFF = MUP_OFF + (size_t)Bb * Tt * 256;

// ---------------- static device scratch ----------------
__device__ u16  g_wp_enc[196608];
__device__ u16  g_wp_pp[131072];
__device__ u16  g_wp_hh[786432];
__device__ u16  g_wp_mulv[131072];
__device__ u16  g_wp_mplp[131072];
__device__ u16  g_wp_phiz[65536];
__device__ u16  g_wp_ih[786432];
__device__ u16  g_wp_dec[12288];
__device__ u16  g_wp_phix[16384];
__device__ float g_h[2][131072];     // fp32 hidden, double-buffered
__device__ u16   g_hb[2][131072];    // bf16 hidden
__device__ u16   g_phx[2][65536];    // bf16 phi_x, double-buffered
__device__ u16   g_encb[65536];
__device__ u16   g_zpb[65536];
__device__ u16   g_phizb[65536];
__device__ float g_mus[65536];
__device__ float g_lvs[65536];
__device__ float g_ghs[393216];

__device__ __forceinline__ u16 f2bf(float f) {
  unsigned u = __builtin_bit_cast(unsigned, f);
  u += 0x7FFFu + ((u >> 16) & 1u);
  return (u16)(u >> 16);
}

struct Args {
  const float *x, *eps;
  const float *b_phix, *b_enc, *b_mu, *b_lv, *b_pp, *b_mup, *b_lvp, *b_phiz, *b_dec, *b_ih, *b_hh;
  float *out;
};

// ---------------- weight pre-pack into MFMA B-fragment layout ----------------
// B-frag for v_mfma_f32_16x16x32_bf16: lane l holds W[k = 32*kk + 8*(l>>4) + i][n = 16*nn + (l&15)]
// packed at dst[((nn*KT + kk)*64 + lane)*8 + i]
__device__ __forceinline__ u16* sel_wp(int sel) {
  switch (sel) {
    case 0: return g_wp_enc;  case 1: return g_wp_pp;   case 2: return g_wp_hh;
    case 3: return g_wp_mulv; case 4: return g_wp_mplp; case 5: return g_wp_phiz;
    case 6: return g_wp_ih;   case 7: return g_wp_dec;  default: return g_wp_phix;
  }
}

__global__ void pack_w(const float* __restrict__ src, int KT, int Nsrc,
                       int sel, int nnStart, int nnCount, int colBase) {
  int gid = blockIdx.x * 256 + threadIdx.x;
  int total = nnCount * KT * 64;
  if (gid >= total) return;
  u16* dstBase = sel_wp(sel);
  int lane = gid & 63;
  int rem  = gid >> 6;
  int kk   = rem % KT;
  int nn   = nnStart + rem / KT;
  int col  = nn * 16 + (lane & 15) - colBase;
  int krow = kk * 32 + ((lane >> 4) << 3);
  bool ok = (col >= 0) && (col < Nsrc);
  u16* d = dstBase + ((size_t)(nn * KT + kk) * 64 + lane) * 8;
#pragma unroll
  for (int i = 0; i < 8; ++i)
    d[i] = ok ? f2bf(src[(size_t)(krow + i) * Nsrc + col]) : (u16)0;
}

// ---------------- fragment loads ----------------
__device__ __forceinline__ short8v loadB(const u16* wp, int KT, int nn, int kk, int lane) {
  return *(const short8v*)(wp + ((size_t)(nn * KT + kk) * 64 + lane) * 8);
}
// A-frag: lane l holds A[row = m0 + (l&15)][k = kcol + 8*(l>>4) + i], contiguous 16B
__device__ __forceinline__ short8v loadA_bf(const u16* buf, int stride, int m0, int kcol, int lane) {
  return *(const short8v*)(buf + (size_t)(m0 + (lane & 15)) * stride + kcol + ((lane >> 4) << 3));
}
__device__ __forceinline__ short8v cvt8(const float* s) {
  short8v r;
#pragma unroll
  for (int i = 0; i < 8; ++i) r[i] = (short)f2bf(s[i]);
  return r;
}

__device__ __forceinline__ float sigm_(float x) { return 1.f / (1.f + __expf(-x)); }
__device__ __forceinline__ float tanh_(float x) {
  x = fminf(fmaxf(x, -15.f), 15.f);
  float e = __expf(2.f * x);
  return (e - 1.f) / (e + 1.f);
}

// ---------------- jobs (each = one wave, 32x64 output tile unless noted) ----------------

// enc = relu([phi_x | h] @ W_enc + b_enc), K=768, N=256
__device__ void job_enc(const Args& a, int j, int t, int lane) {
  const u16* phx = g_phx[t & 1];
  const u16* hb  = g_hb[t & 1];
  const int m0 = (j >> 2) * 32, n0 = (j & 3) * 64, nn0 = n0 >> 4;
  f32x4 acc[2][4];
#pragma unroll
  for (int m = 0; m < 2; ++m)
#pragma unroll
    for (int f = 0; f < 4; ++f) acc[m][f] = (f32x4){0.f, 0.f, 0.f, 0.f};
  for (int kk = 0; kk < 24; ++kk) {
    short8v a0, a1;
    if (kk < 8) { a0 = loadA_bf(phx, 256, m0, kk * 32, lane); a1 = loadA_bf(phx, 256, m0 + 16, kk * 32, lane); }
    else        { a0 = loadA_bf(hb, 512, m0, (kk - 8) * 32, lane); a1 = loadA_bf(hb, 512, m0 + 16, (kk - 8) * 32, lane); }
#pragma unroll
    for (int f = 0; f < 4; ++f) {
      short8v b = loadB(g_wp_enc, 24, nn0 + f, kk, lane);
      acc[0][f] = MFMA_BF16(a0, b, acc[0][f]);
      acc[1][f] = MFMA_BF16(a1, b, acc[1][f]);
    }
  }
  const int cl = lane & 15, rb = (lane >> 4) << 2;
#pragma unroll
  for (int m = 0; m < 2; ++m)
#pragma unroll
    for (int f = 0; f < 4; ++f) {
      int col = n0 + f * 16 + cl;
      float bb = a.b_enc[col];
#pragma unroll
      for (int r = 0; r < 4; ++r) {
        int row = m0 + m * 16 + rb + r;
        g_encb[(size_t)row * 256 + col] = f2bf(fmaxf(acc[m][f][r] + bb, 0.f));
      }
    }
}

// zp = relu(h @ W_pp + b_pp), K=512, N=256
__device__ void job_zp(const Args& a, int j, int t, int lane) {
  const u16* hb = g_hb[t & 1];
  const int m0 = (j >> 2) * 32, n0 = (j & 3) * 64, nn0 = n0 >> 4;
  f32x4 acc[2][4];
#pragma unroll
  for (int m = 0; m < 2; ++m)
#pragma unroll
    for (int f = 0; f < 4; ++f) acc[m][f] = (f32x4){0.f, 0.f, 0.f, 0.f};
  for (int kk = 0; kk < 16; ++kk) {
    short8v a0 = loadA_bf(hb, 512, m0, kk * 32, lane);
    short8v a1 = loadA_bf(hb, 512, m0 + 16, kk * 32, lane);
#pragma unroll
    for (int f = 0; f < 4; ++f) {
      short8v b = loadB(g_wp_pp, 16, nn0 + f, kk, lane);
      acc[0][f] = MFMA_BF16(a0, b, acc[0][f]);
      acc[1][f] = MFMA_BF16(a1, b, acc[1][f]);
    }
  }
  const int cl = lane & 15, rb = (lane >> 4) << 2;
#pragma unroll
  for (int m = 0; m < 2; ++m)
#pragma unroll
    for (int f = 0; f < 4; ++f) {
      int col = n0 + f * 16 + cl;
      float bb = a.b_pp[col];
#pragma unroll
      for (int r = 0; r < 4; ++r) {
        int row = m0 + m * 16 + rb + r;
        g_zpb[(size_t)row * 256 + col] = f2bf(fmaxf(acc[m][f][r] + bb, 0.f));
      }
    }
}

// gh = h @ W_hh + b_hh, K=512, N=1536 (fp32 out)
__device__ void job_gh(const Args& a, int j, int t, int lane) {
  const u16* hb = g_hb[t & 1];
  const int m0 = (j / 24) * 32, n0 = (j % 24) * 64, nn0 = n0 >> 4;
  f32x4 acc[2][4];
#pragma unroll
  for (int m = 0; m < 2; ++m)
#pragma unroll
    for (int f = 0; f < 4; ++f) acc[m][f] = (f32x4){0.f, 0.f, 0.f, 0.f};
  for (int kk = 0; kk < 16; ++kk) {
    short8v a0 = loadA_bf(hb, 512, m0, kk * 32, lane);
    short8v a1 = loadA_bf(hb, 512, m0 + 16, kk * 32, lane);
#pragma unroll
    for (int f = 0; f < 4; ++f) {
      short8v b = loadB(g_wp_hh, 16, nn0 + f, kk, lane);
      acc[0][f] = MFMA_BF16(a0, b, acc[0][f]);
      acc[1][f] = MFMA_BF16(a1, b, acc[1][f]);
    }
  }
  const int cl = lane & 15, rb = (lane >> 4) << 2;
#pragma unroll
  for (int m = 0; m < 2; ++m)
#pragma unroll
    for (int f = 0; f < 4; ++f) {
      int col = n0 + f * 16 + cl;
      float bb = a.b_hh[col];
#pragma unroll
      for (int r = 0; r < 4; ++r) {
        int row = m0 + m * 16 + rb + r;
        g_ghs[(size_t)row * 1536 + col] = acc[m][f][r] + bb;
      }
    }
}

// phi_x(tt) = relu(x[:,tt,:] @ W_phix + b_phix), K=64, N=256; dst = g_phx[tt&1]
__device__ void job_phix(const Args& a, int j, int tt, int lane) {
  u16* dst = g_phx[tt & 1];
  const int m0 = (j >> 2) * 32, n0 = (j & 3) * 64, nn0 = n0 >> 4;
  const float* xb = a.x + (size_t)tt * 64;  // + row*(T*X) + k
  f32x4 acc[2][4];
#pragma unroll
  for (int m = 0; m < 2; ++m)
#pragma unroll
    for (int f = 0; f < 4; ++f) acc[m][f] = (f32x4){0.f, 0.f, 0.f, 0.f};
  for (int kk = 0; kk < 2; ++kk) {
    int kc = kk * 32 + ((lane >> 4) << 3);
    short8v a0 = cvt8(xb + (size_t)(m0 + (lane & 15)) * 32768 + kc);
    short8v a1 = cvt8(xb + (size_t)(m0 + 16 + (lane & 15)) * 32768 + kc);
#pragma unroll
    for (int f = 0; f < 4; ++f) {
      short8v b = loadB(g_wp_phix, 2, nn0 + f, kk, lane);
      acc[0][f] = MFMA_BF16(a0, b, acc[0][f]);
      acc[1][f] = MFMA_BF16(a1, b, acc[1][f]);
    }
  }
  const int cl = lane & 15, rb = (lane >> 4) << 2;
#pragma unroll
  for (int m = 0; m < 2; ++m)
#pragma unroll
    for (int f = 0; f < 4; ++f) {
      int col = n0 + f * 16 + cl;
      float bb = a.b_phix[col];
#pragma unroll
      for (int r = 0; r < 4; ++r) {
        int row = m0 + m * 16 + rb + r;
        dst[(size_t)row * 256 + col] = f2bf(fmaxf(acc[m][f][r] + bb, 0.f));
      }
    }
}

// [mu | lv] = enc @ [W_mu|W_lv] + b, K=256, N=512; store ws + d_out
__device__ void job_mulv(const Args& a, int j, int t, int lane) {
  const int m0 = (j >> 3) * 32, n0 = (j & 7) * 64, nn0 = n0 >> 4;
  f32x4 acc[2][4];
#pragma unroll
  for (int m = 0; m < 2; ++m)
#pragma unroll
    for (int f = 0; f < 4; ++f) acc[m][f] = (f32x4){0.f, 0.f, 0.f, 0.f};
  for (int kk = 0; kk < 8; ++kk) {
    short8v a0 = loadA_bf(g_encb, 256, m0, kk * 32, lane);
    short8v a1 = loadA_bf(g_encb, 256, m0 + 16, kk * 32, lane);
#pragma unroll
    for (int f = 0; f < 4; ++f) {
      short8v b = loadB(g_wp_mulv, 8, nn0 + f, kk, lane);
      acc[0][f] = MFMA_BF16(a0, b, acc[0][f]);
      acc[1][f] = MFMA_BF16(a1, b, acc[1][f]);
    }
  }
  const int cl = lane & 15, rb = (lane >> 4) << 2;
#pragma unroll
  for (int m = 0; m < 2; ++m)
#pragma unroll
    for (int f = 0; f < 4; ++f) {
      int col = n0 + f * 16 + cl;
      bool isMu = col < 256;
      int c = isMu ? col : col - 256;
      float bb = isMu ? a.b_mu[c] : a.b_lv[c];
#pragma unroll
      for (int r = 0; r < 4; ++r) {
        int row = m0 + m * 16 + rb + r;
        float v = acc[m][f][r] + bb;
        (isMu ? g_mus : g_lvs)[(size_t)row * 256 + c] = v;
        a.out[(isMu ? MU_OFF : LV_OFF) + ((size_t)row * 512 + t) * 256 + c] = v;
      }
    }
}

// [mup | lvp] = zp @ [W_mup|W_lvp] + b, K=256, N=512; d_out only
__device__ void job_mplp(const Args& a, int j, int t, int lane) {
  const int m0 = (j >> 3) * 32, n0 = (j & 7) * 64, nn0 = n0 >> 4;
  f32x4 acc[2][4];
#pragma unroll
  for (int m = 0; m < 2; ++m)
#pragma unroll
    for (int f = 0; f < 4; ++f) acc[m][f] = (f32x4){0.f, 0.f, 0.f, 0.f};
  for (int kk = 0; kk < 8; ++kk) {
    short8v a0 = loadA_bf(g_zpb, 256, m0, kk * 32, lane);
    short8v a1 = loadA_bf(g_zpb, 256, m0 + 16, kk * 32, lane);
#pragma unroll
    for (int f = 0; f < 4; ++f) {
      short8v b = loadB(g_wp_mplp, 8, nn0 + f, kk, lane);
      acc[0][f] = MFMA_BF16(a0, b, acc[0][f]);
      acc[1][f] = MFMA_BF16(a1, b, acc[1][f]);
    }
  }
  const int cl = lane & 15, rb = (lane >> 4) << 2;
#pragma unroll
  for (int m = 0; m < 2; ++m)
#pragma unroll
    for (int f = 0; f < 4; ++f) {
      int col = n0 + f * 16 + cl;
      bool isMu = col < 256;
      int c = isMu ? col : col - 256;
      float bb = isMu ? a.b_mup[c] : a.b_lvp[c];
#pragma unroll
      for (int r = 0; r < 4; ++r) {
        int row = m0 + m * 16 + rb + r;
        a.out[(isMu ? MUP_OFF : LVP_OFF) + ((size_t)row * 512 + t) * 256 + c] = acc[m][f][r] + bb;
      }
    }
}

// phi_z = relu(z @ W_phiz + b), z = mu + eps*exp(0.5 lv) built on the fly, K=256, N=256
__device__ void job_phiz(const Args& a, int j, int t, int lane) {
  const int m0 = (j >> 2) * 32, n0 = (j & 3) * 64, nn0 = n0 >> 4;
  f32x4 acc[2][4];
#pragma unroll
  for (int m = 0; m < 2; ++m)
#pragma unroll
    for (int f = 0; f < 4; ++f) acc[m][f] = (f32x4){0.f, 0.f, 0.f, 0.f};
  for (int kk = 0; kk < 8; ++kk) {
    short8v av[2];
#pragma unroll
    for (int m = 0; m < 2; ++m) {
      int row = m0 + m * 16 + (lane & 15);
      int kc = kk * 32 + ((lane >> 4) << 3);
      const float* mp = g_mus + (size_t)row * 256 + kc;
      const float* lp = g_lvs + (size_t)row * 256 + kc;
      const float* ep = a.eps + ((size_t)row * 512 + t) * 256 + kc;
#pragma unroll
      for (int i = 0; i < 8; ++i)
        av[m][i] = (short)f2bf(mp[i] + ep[i] * __expf(0.5f * lp[i]));
    }
#pragma unroll
    for (int f = 0; f < 4; ++f) {
      short8v b = loadB(g_wp_phiz, 8, nn0 + f, kk, lane);
      acc[0][f] = MFMA_BF16(av[0], b, acc[0][f]);
      acc[1][f] = MFMA_BF16(av[1], b, acc[1][f]);
    }
  }
  const int cl = lane & 15, rb = (lane >> 4) << 2;
#pragma unroll
  for (int m = 0; m < 2; ++m)
#pragma unroll
    for (int f = 0; f < 4; ++f) {
      int col = n0 + f * 16 + cl;
      float bb = a.b_phiz[col];
#pragma unroll
      for (int r = 0; r < 4; ++r) {
        int row = m0 + m * 16 + rb + r;
        g_phizb[(size_t)row * 256 + col] = f2bf(fmaxf(acc[m][f][r] + bb, 0.f));
      }
    }
}

// gi (3 gates, 64 GRU-cols each) = [phi_x | phi_z] @ W_ih, K=512; epilogue does full GRU cell.
// 16-row job: j -> mt (16), ng (8)
__device__ void job_gru(const Args& a, int j, int t, int lane) {
  const u16* phx = g_phx[t & 1];
  const float* ho = g_h[t & 1];
  float* hn = g_h[(t + 1) & 1];
  u16* hbn = g_hb[(t + 1) & 1];
  const int m0 = (j >> 3) * 16, ng = j & 7;
  f32x4 acc[3][4];
#pragma unroll
  for (int g = 0; g < 3; ++g)
#pragma unroll
    for (int f = 0; f < 4; ++f) acc[g][f] = (f32x4){0.f, 0.f, 0.f, 0.f};
  for (int kk = 0; kk < 16; ++kk) {
    short8v av = (kk < 8) ? loadA_bf(phx, 256, m0, kk * 32, lane)
                          : loadA_bf(g_phizb, 256, m0, (kk - 8) * 32, lane);
#pragma unroll
    for (int g = 0; g < 3; ++g)
#pragma unroll
      for (int f = 0; f < 4; ++f) {
        short8v b = loadB(g_wp_ih, 16, g * 32 + ng * 4 + f, kk, lane);
        acc[g][f] = MFMA_BF16(av, b, acc[g][f]);
      }
  }
  const int cl = lane & 15, rb = (lane >> 4) << 2;
#pragma unroll
  for (int f = 0; f < 4; ++f) {
    int jcol = ng * 64 + f * 16 + cl;  // 0..511
#pragma unroll
    for (int r = 0; r < 4; ++r) {
      int row = m0 + rb + r;
      float ir = acc[0][f][r] + a.b_ih[jcol];
      float iz = acc[1][f][r] + a.b_ih[512 + jcol];
      float in_ = acc[2][f][r] + a.b_ih[1024 + jcol];
      const float* ghrow = g_ghs + (size_t)row * 1536;
      float hr = ghrow[jcol], hz = ghrow[512 + jcol], hnn = ghrow[1024 + jcol];
      float rg = sigm_(ir + hr);
      float zg = sigm_(iz + hz);
      float ngate = tanh_(in_ + rg * hnn);
      float hold = ho[(size_t)row * 512 + jcol];
      float hv = (1.f - zg) * ngate + zg * hold;
      hn[(size_t)row * 512 + jcol] = hv;
      hbn[(size_t)row * 512 + jcol] = f2bf(hv);
    }
  }
}

// out = relu([phi_z | h] @ W_dec + b_dec), K=768, N=2 (padded to 16)
__device__ void job_outdec(const Args& a, int j, int t, int lane) {
  const u16* hb = g_hb[t & 1];
  const int m0 = j * 32;
  f32x4 acc[2];
  acc[0] = (f32x4){0.f, 0.f, 0.f, 0.f};
  acc[1] = (f32x4){0.f, 0.f, 0.f, 0.f};
  for (int kk = 0; kk < 24; ++kk) {
    short8v a0, a1;
    if (kk < 8) { a0 = loadA_bf(g_phizb, 256, m0, kk * 32, lane); a1 = loadA_bf(g_phizb, 256, m0 + 16, kk * 32, lane); }
    else        { a0 = loadA_bf(hb, 512, m0, (kk - 8) * 32, lane); a1 = loadA_bf(hb, 512, m0 + 16, (kk - 8) * 32, lane); }
    short8v b = loadB(g_wp_dec, 24, 0, kk, lane);
    acc[0] = MFMA_BF16(a0, b, acc[0]);
    acc[1] = MFMA_BF16(a1, b, acc[1]);
  }
  const int cl = lane & 15, rb = (lane >> 4) << 2;
  if (cl < 2) {
#pragma unroll
    for (int m = 0; m < 2; ++m)
#pragma unroll
      for (int r = 0; r < 4; ++r) {
        int row = m0 + m * 16 + rb + r;
        float v = fmaxf(acc[m][r] + a.b_dec[cl], 0.f);
        a.out[(size_t)row * 1024 + (size_t)t * 2 + cl] = v;
      }
  }
}

// ---------------- phase kernels (plain launches, stream-ordered deps) ----------------

// prologue: zero h[0], hb[0]; phi_x(0). 16 blocks x 256.
__global__ __launch_bounds__(256) void k_prologue(Args a) {
  int lane = threadIdx.x & 63;
  if (blockIdx.x < 8) {
    for (int g = blockIdx.x * 256 + threadIdx.x; g < 131072; g += 8 * 256) {
      g_h[0][g] = 0.f;
      g_hb[0][g] = 0;
    }
  } else {
    int j = (blockIdx.x - 8) * 4 + (threadIdx.x >> 6);  // 0..31
    job_phix(a, j, 0, lane);
  }
}

// P1: enc(32) zp(32) gh(192) phix(t+1)(32) -> 288 jobs, 72 blocks x 256
__global__ __launch_bounds__(256) void k_p1(Args a, int t) {
  int lane = threadIdx.x & 63;
  int j = blockIdx.x * 4 + (threadIdx.x >> 6);
  if (j < 32) job_enc(a, j, t, lane);
  else if (j < 64) job_zp(a, j - 32, t, lane);
  else if (j < 256) job_gh(a, j - 64, t, lane);
  else if (t + 1 < Tt) job_phix(a, j - 256, t + 1, lane);
}

// P2: mulv(64) + mplp(64) -> 128 jobs, 32 blocks
__global__ __launch_bounds__(256) void k_p2(Args a, int t) {
  int lane = threadIdx.x & 63;
  int j = blockIdx.x * 4 + (threadIdx.x >> 6);
  if (j < 64) job_mulv(a, j, t, lane);
  else job_mplp(a, j - 64, t, lane);
}

// P3: phiz(32) -> 8 blocks
__global__ __launch_bounds__(256) void k_p3(Args a, int t) {
  int lane = threadIdx.x & 63;
  int j = blockIdx.x * 4 + (threadIdx.x >> 6);
  job_phiz(a, j, t, lane);
}

// P4: gru(128) + outdec(8) -> 136 jobs, 34 blocks
__global__ __launch_bounds__(256) void k_p4(Args a, int t) {
  int lane = threadIdx.x & 63;
  int j = blockIdx.x * 4 + (threadIdx.x >> 6);
  if (j < 128) job_gru(a, j, t, lane);
  else job_outdec(a, j - 128, t, lane);
}

// ---------------- host launch ----------------
extern "C" void kernel_launch(void* const* d_in, const int* in_sizes, int n_in,
                              void* d_out, int out_size, void* d_ws, size_t ws_size,
                              hipStream_t stream) {
  const float* x      = (const float*)d_in[0];
  const float* eps    = (const float*)d_in[1];
  const float* W_phix = (const float*)d_in[2];  const float* b_phix = (const float*)d_in[3];
  const float* W_enc  = (const float*)d_in[4];  const float* b_enc  = (const float*)d_in[5];
  const float* W_mu   = (const float*)d_in[6];  const float* b_mu   = (const float*)d_in[7];
  const float* W_lv   = (const float*)d_in[8];  const float* b_lv   = (const float*)d_in[9];
  const float* W_pp   = (const float*)d_in[10]; const float* b_pp   = (const float*)d_in[11];
  const float* W_mup  = (const float*)d_in[12]; const float* b_mup  = (const float*)d_in[13];
  const float* W_lvp  = (const float*)d_in[14]; const float* b_lvp  = (const float*)d_in[15];
  const float* W_phiz = (const float*)d_in[16]; const float* b_phiz = (const float*)d_in[17];
  const float* W_dec  = (const float*)d_in[18]; const float* b_dec  = (const float*)d_in[19];
  // setup_inputs order: W_ih, W_hh, b_ih, b_hh  (rounds 1-3 had these swapped -> OOB pack read -> abort)
  const float* W_ih   = (const float*)d_in[20];
  const float* W_hh   = (const float*)d_in[21];
  const float* b_ih   = (const float*)d_in[22];
  const float* b_hh   = (const float*)d_in[23];
  (void)d_ws; (void)ws_size; (void)in_sizes; (void)n_in; (void)out_size;

  auto packL = [&](const float* src, int KT, int Nsrc, int sel, int nnStart, int nnCount, int colBase) {
    int total = nnCount * KT * 64;
    pack_w<<<(total + 255) / 256, 256, 0, stream>>>(src, KT, Nsrc, sel, nnStart, nnCount, colBase);
  };
  packL(W_enc, 24, 256, 0, 0, 16, 0);
  packL(W_pp, 16, 256, 1, 0, 16, 0);
  packL(W_hh, 16, 1536, 2, 0, 96, 0);
  packL(W_mu, 8, 256, 3, 0, 16, 0);
  packL(W_lv, 8, 256, 3, 16, 16, 256);
  packL(W_mup, 8, 256, 4, 0, 16, 0);
  packL(W_lvp, 8, 256, 4, 16, 16, 256);
  packL(W_phiz, 8, 256, 5, 0, 16, 0);
  packL(W_ih, 16, 1536, 6, 0, 96, 0);
  packL(W_dec, 24, 2, 7, 0, 1, 0);
  packL(W_phix, 2, 256, 8, 0, 16, 0);

  Args a;
  a.x = x; a.eps = eps;
  a.b_phix = b_phix; a.b_enc = b_enc; a.b_mu = b_mu; a.b_lv = b_lv; a.b_pp = b_pp;
  a.b_mup = b_mup; a.b_lvp = b_lvp; a.b_phiz = b_phiz; a.b_dec = b_dec; a.b_ih = b_ih; a.b_hh = b_hh;
  a.out = (float*)d_out;

  k_prologue<<<16, 256, 0, stream>>>(a);
  for (int t = 0; t < Tt; ++t) {
    k_p1<<<72, 256, 0, stream>>>(a, t);
    k_p2<<<32, 256, 0, stream>>>(a, t);
    k_p3<<<8, 256, 0, stream>>>(a, t);
    k_p4<<<34, 256, 0, stream>>>(a, t);
  }
}